// Round 13
// baseline (648.415 us; speedup 1.0000x reference)
//
#include <hip/hip_runtime.h>

#define D 128
#define OUTD 384
#define SLOPE 0.2f
#define BSH 7                  // bucket = row >> 7  (128 rows/bucket)
#define BROWS 128
#define MAXNB 2048
#define FCAP 4736              // bucket LDS stage capacity (avg 4096 + slack)
#define SPAN 8192              // edges per scatter block
#define SCT 512

typedef __attribute__((ext_vector_type(8))) short bf16x8;
typedef __attribute__((ext_vector_type(4))) float f32x4;

__device__ __forceinline__ unsigned f2bf(float f) {   // round-to-nearest-even bf16
    unsigned u = __float_as_uint(f);
    return (u + 0x7FFFu + ((u >> 16) & 1u)) >> 16;
}

__device__ __forceinline__ void nt_store_f4(float4 v, float* p) {
    f32x4 t = {v.x, v.y, v.z, v.w};
    __builtin_nontemporal_store(t, (f32x4*)p);
}

// ---------------- one-time weight prep: Wt[n][k] = bf16(W[k][n]) ----------------
__global__ __launch_bounds__(256) void wt_prep(const float* __restrict__ W0,
                                               const float* __restrict__ W1,
                                               const float* __restrict__ W2,
                                               const float* __restrict__ W3,
                                               unsigned short* __restrict__ wt) {
    const float* Ws[4] = {W0, W1, W2, W3};
    const float* W = Ws[blockIdx.x];
    unsigned short* o = wt + (size_t)blockIdx.x * 16384;
    for (int i = threadIdx.x; i < 16384; i += 256) {
        int k = i >> 7, n = i & 127;
        o[(size_t)n * 128 + k] = (unsigned short)f2bf(W[(size_t)k * 128 + n]);
    }
}

// ---------------- MFMA GEMM: featb[r] = bf16( (rowscale[r]*in[r*pitch]) @ W ) -------------
#define GR 64
#define APAD 136
__global__ __launch_bounds__(256) void gemm_mfma(const float* __restrict__ in, int pitch,
                                                 const unsigned short* __restrict__ Wt,
                                                 unsigned short* __restrict__ featb,
                                                 const float* __restrict__ rowscale,
                                                 float* __restrict__ rawout,
                                                 int nrows) {
    __shared__ unsigned short sA[GR * APAD];     // 17.4 KB
    __shared__ unsigned short sW[128 * APAD];    // 34.8 KB
    int tid = threadIdx.x;
    int row0 = blockIdx.x * GR;
    int nr = min(GR, nrows - row0);

    for (int i = tid; i < GR * 32; i += 256) {
        int r = i >> 5, c4 = (i & 31) * 4;
        unsigned lo = 0, hi = 0;
        if (r < nr) {
            float4 t = *(const float4*)&in[(size_t)(row0 + r) * pitch + c4];
            if (rawout)
                nt_store_f4(t, &rawout[(size_t)(row0 + r) * OUTD + c4]);
            if (rowscale) {
                float s = rowscale[row0 + r];
                t.x *= s; t.y *= s; t.z *= s; t.w *= s;
            }
            lo = f2bf(t.x) | (f2bf(t.y) << 16);
            hi = f2bf(t.z) | (f2bf(t.w) << 16);
        }
        uint2 pk = {lo, hi};
        *(uint2*)&sA[r * APAD + c4] = pk;
    }
    for (int i = tid; i < 128 * 16; i += 256) {
        int n = i >> 4, k8 = (i & 15) * 8;
        *(uint4*)&sW[n * APAD + k8] = *(const uint4*)&Wt[(size_t)n * 128 + k8];
    }
    __syncthreads();

    int l  = tid & 63;
    int w  = tid >> 6;
    int lr = l & 15;
    int lk = (l >> 4) * 8;

    f32x4 acc[8];
#pragma unroll
    for (int t = 0; t < 8; ++t) acc[t] = (f32x4){0.f, 0.f, 0.f, 0.f};

#pragma unroll
    for (int k0 = 0; k0 < 128; k0 += 32) {
        bf16x8 af = *(const bf16x8*)&sA[(16 * w + lr) * APAD + k0 + lk];
#pragma unroll
        for (int t = 0; t < 8; ++t) {
            bf16x8 bf = *(const bf16x8*)&sW[(t * 16 + lr) * APAD + k0 + lk];
            acc[t] = __builtin_amdgcn_mfma_f32_16x16x32_bf16(af, bf, acc[t], 0, 0, 0);
        }
    }

    int rbase = 16 * w + (l >> 4) * 4;
#pragma unroll
    for (int t = 0; t < 8; ++t) {
#pragma unroll
        for (int q = 0; q < 4; ++q) {
            int r = rbase + q;
            if (r < nr)
                featb[(size_t)(row0 + r) * D + t * 16 + lr] = (unsigned short)f2bf(acc[t][q]);
        }
    }
}

// ================= CSR build (fixed-capacity buckets) =================
__global__ __launch_bounds__(256) void init_cursors(int* __restrict__ bcursor,
                                                    int NB, int cap) {
    int b = blockIdx.x * 256 + threadIdx.x;
    if (b < NB) bcursor[b * 16] = b * cap;
}

#define EMIT(r, c, v)                                                              \
    {                                                                              \
        int b_ = (r) >> BSH;                                                       \
        int pos_ = atomicAdd(&hist[b_], 1);                                        \
        if ((unsigned)(pos_ - b_ * cap) < (unsigned)cap)                           \
            etmp[pos_] = make_uint2(((unsigned)((r) & (BROWS - 1)) << 18) |        \
                                    (unsigned)(c), __float_as_uint(v));            \
    }

__global__ __launch_bounds__(SCT) void chunk_scatter(const int* __restrict__ rows,
                                                     const int* __restrict__ cols,
                                                     const float* __restrict__ vals,
                                                     int* __restrict__ bcursor,
                                                     uint2* __restrict__ etmp,
                                                     int nnz, int NB, int cap) {
    __shared__ int hist[MAXNB];
    int tid = threadIdx.x;
    int lo  = blockIdx.x * SPAN;
    int hi  = min(lo + SPAN, nnz);
    if (lo >= nnz) return;

    for (int i = tid; i < NB; i += SCT) hist[i] = 0;
    __syncthreads();

    int4 r4[4];
#pragma unroll
    for (int q = 0; q < 4; ++q) {
        int e = lo + (q * SCT + tid) * 4;
        if (e + 3 < hi) {
            r4[q] = *(const int4*)&rows[e];
            atomicAdd(&hist[r4[q].x >> BSH], 1);
            atomicAdd(&hist[r4[q].y >> BSH], 1);
            atomicAdd(&hist[r4[q].z >> BSH], 1);
            atomicAdd(&hist[r4[q].w >> BSH], 1);
        } else {
            int t0 = (e + 0 < hi) ? rows[e + 0] : -1;
            int t1 = (e + 1 < hi) ? rows[e + 1] : -1;
            int t2 = (e + 2 < hi) ? rows[e + 2] : -1;
            int t3 = (e + 3 < hi) ? rows[e + 3] : -1;
            if (t0 >= 0) atomicAdd(&hist[t0 >> BSH], 1);
            if (t1 >= 0) atomicAdd(&hist[t1 >> BSH], 1);
            if (t2 >= 0) atomicAdd(&hist[t2 >> BSH], 1);
            if (t3 >= 0) atomicAdd(&hist[t3 >> BSH], 1);
            r4[q] = make_int4(t0, t1, t2, t3);
        }
    }
    __syncthreads();

    for (int i = tid; i < NB; i += SCT) {
        int c = hist[i];
        hist[i] = c ? atomicAdd(&bcursor[i * 16], c) : 0;
    }
    __syncthreads();

#pragma unroll
    for (int q = 0; q < 4; ++q) {
        int e = lo + (q * SCT + tid) * 4;
        if (e + 3 < hi) {
            int4   c4 = *(const int4*)&cols[e];
            float4 v4 = *(const float4*)&vals[e];
            EMIT(r4[q].x, c4.x, v4.x);
            EMIT(r4[q].y, c4.y, v4.y);
            EMIT(r4[q].z, c4.z, v4.z);
            EMIT(r4[q].w, c4.w, v4.w);
        } else {
            int rr0 = r4[q].x, rr1 = r4[q].y, rr2 = r4[q].z, rr3 = r4[q].w;
            if (rr0 >= 0) { EMIT(rr0, cols[e + 0], vals[e + 0]); }
            if (rr1 >= 0) { EMIT(rr1, cols[e + 1], vals[e + 1]); }
            if (rr2 >= 0) { EMIT(rr2, cols[e + 2], vals[e + 2]); }
            if (rr3 >= 0) { EMIT(rr3, cols[e + 3], vals[e + 3]); }
        }
    }
}

// ===== shared gather macro =====
#define ACCQ(vbits, g)                                             \
    {                                                              \
        float v = __uint_as_float(vbits);                          \
        acc0.x += v * __uint_as_float((g).x << 16);                \
        acc0.y += v * __uint_as_float((g).x & 0xFFFF0000u);        \
        acc0.z += v * __uint_as_float((g).y << 16);                \
        acc0.w += v * __uint_as_float((g).y & 0xFFFF0000u);        \
        acc1.x += v * __uint_as_float((g).z << 16);                \
        acc1.y += v * __uint_as_float((g).z & 0xFFFF0000u);        \
        acc1.z += v * __uint_as_float((g).w << 16);                \
        acc1.w += v * __uint_as_float((g).w & 0xFFFF0000u);        \
    }

// ================ fused: per-bucket sort (emit sorted ep + row_start/rend) + layer-0 SpMM
// Block = 1 bucket (128 rows), 512 thr = 8 waves; wave w consumes rows 16w..16w+15
// from its own just-written (L2-hot) sorted edges.
#define FTH 512
__global__ __launch_bounds__(FTH) void spmm_sort_fused(const int* __restrict__ bcursor,
                                                       uint2* __restrict__ ep,
                                                       int* __restrict__ row_start,
                                                       int* __restrict__ rend,
                                                       const unsigned short* __restrict__ featb,
                                                       float* __restrict__ out,
                                                       float* __restrict__ nsave,
                                                       int col_off, int N, int cap) {
    __shared__ uint2 ed[FCAP];                   // 37.9 KB
    __shared__ int rcnt[BROWS], rbase[BROWS], rsLds[BROWS];
    __shared__ int wsum[2];
    int b   = blockIdx.x;
    int s   = b * cap;
    int len = bcursor[b * 16] - s;
    if (len > cap) len = cap;
    int tid = threadIdx.x;
    if (tid < BROWS) rcnt[tid] = 0;
    __syncthreads();

    // stage + per-row count
    for (int i = tid; i < len; i += FTH) {
        uint2 t = ep[s + i];
        ed[i] = t;
        atomicAdd(&rcnt[t.x >> 18], 1);
    }
    __syncthreads();

    // exclusive scan of 128 counts (2 waves)
    int lane = tid & 63, wid = tid >> 6;
    int c = (tid < BROWS) ? rcnt[tid] : 0;
    int incl = c;
#pragma unroll
    for (int off = 1; off < 64; off <<= 1) {
        int t = __shfl_up(incl, off);
        if (lane >= off) incl += t;
    }
    if (tid < BROWS && lane == 63) wsum[wid] = incl;
    __syncthreads();
    if (tid < BROWS) {
        int woff = (wid == 1) ? wsum[0] : 0;
        int excl = woff + incl - c;
        rbase[tid] = s + excl;
        rsLds[tid] = s + excl;
        int row = b * BROWS + tid;
        if (row < N) { row_start[row] = s + excl; rend[row] = s + excl + c; }
    }
    __syncthreads();

    // permute to sorted order in global (this block's own L2)
    for (int i = tid; i < len; i += FTH) {
        uint2 t = ed[i];
        int pos = atomicAdd(&rbase[t.x >> 18], 1);
        ep[pos] = make_uint2(t.x & 0x3FFFFu, t.y);
    }
    __syncthreads();

    // ---- layer-0 SpMM consumption: wave wid handles rows wid*16 .. wid*16+15 ----
    int j = lane & 15;      // dim group
    int h = lane >> 4;      // edge slot
    for (int rr = 0; rr < 16; ++rr) {
        int rloc = wid * 16 + rr;
        int row  = b * BROWS + rloc;
        if (row >= N) break;
        int sE = rsLds[rloc];
        int eE = sE + rcnt[rloc];

        float4 acc0 = {0.f, 0.f, 0.f, 0.f};
        float4 acc1 = {0.f, 0.f, 0.f, 0.f};
        int i = sE;
        for (; i + 16 <= eE; i += 16) {
            uint2 eA = ep[i + h];
            uint2 eB = ep[i + 4 + h];
            uint2 eC = ep[i + 8 + h];
            uint2 eD = ep[i + 12 + h];
            uint4 gA = *(const uint4*)&featb[(size_t)eA.x * D + j * 8];
            uint4 gB = *(const uint4*)&featb[(size_t)eB.x * D + j * 8];
            uint4 gC = *(const uint4*)&featb[(size_t)eC.x * D + j * 8];
            uint4 gD = *(const uint4*)&featb[(size_t)eD.x * D + j * 8];
            ACCQ(eA.y, gA);
            ACCQ(eB.y, gB);
            ACCQ(eC.y, gC);
            ACCQ(eD.y, gD);
        }
        for (; i + 8 <= eE; i += 8) {
            uint2 eA = ep[i + h];
            uint2 eB = ep[i + 4 + h];
            uint4 gA = *(const uint4*)&featb[(size_t)eA.x * D + j * 8];
            uint4 gB = *(const uint4*)&featb[(size_t)eB.x * D + j * 8];
            ACCQ(eA.y, gA);
            ACCQ(eB.y, gB);
        }
        for (; i < eE; i += 4) {
            int idx = i + h;
            uint2 ev = make_uint2(0u, 0u);
            if (idx < eE) ev = ep[idx];
            uint4 g = *(const uint4*)&featb[(size_t)ev.x * D + j * 8];
            ACCQ(ev.y, g);
        }

#pragma unroll
        for (int m = 16; m <= 32; m <<= 1) {
            acc0.x += __shfl_xor(acc0.x, m);
            acc0.y += __shfl_xor(acc0.y, m);
            acc0.z += __shfl_xor(acc0.z, m);
            acc0.w += __shfl_xor(acc0.w, m);
            acc1.x += __shfl_xor(acc1.x, m);
            acc1.y += __shfl_xor(acc1.y, m);
            acc1.z += __shfl_xor(acc1.z, m);
            acc1.w += __shfl_xor(acc1.w, m);
        }

        acc0.x = (acc0.x > 0.f) ? acc0.x : SLOPE * acc0.x;
        acc0.y = (acc0.y > 0.f) ? acc0.y : SLOPE * acc0.y;
        acc0.z = (acc0.z > 0.f) ? acc0.z : SLOPE * acc0.z;
        acc0.w = (acc0.w > 0.f) ? acc0.w : SLOPE * acc0.w;
        acc1.x = (acc1.x > 0.f) ? acc1.x : SLOPE * acc1.x;
        acc1.y = (acc1.y > 0.f) ? acc1.y : SLOPE * acc1.y;
        acc1.z = (acc1.z > 0.f) ? acc1.z : SLOPE * acc1.z;
        acc1.w = (acc1.w > 0.f) ? acc1.w : SLOPE * acc1.w;

        float ss = acc0.x * acc0.x + acc0.y * acc0.y + acc0.z * acc0.z + acc0.w * acc0.w
                 + acc1.x * acc1.x + acc1.y * acc1.y + acc1.z * acc1.z + acc1.w * acc1.w;
#pragma unroll
        for (int m = 8; m >= 1; m >>= 1) ss += __shfl_xor(ss, m);
        float nm = fmaxf(sqrtf(ss), 1e-12f);
        float sc = 1.0f / nm;

        if (lane == 0) nsave[row] = nm;
        if (h == 0) {
            float* dst = &out[(size_t)row * OUTD + col_off + j * 8];
            float4 o0 = {acc0.x * sc, acc0.y * sc, acc0.z * sc, acc0.w * sc};
            float4 o1 = {acc1.x * sc, acc1.y * sc, acc1.z * sc, acc1.w * sc};
            *(float4*)&dst[0] = o0;
            *(float4*)&dst[4] = o1;
        }
    }
}

// ================= CSR SpMM v4 (layer 1): wave per row, 4 edges per gather ==========
__global__ __launch_bounds__(256) void spmm_csr4(const uint2* __restrict__ ep,
                                                 const int* __restrict__ rstart,
                                                 const int* __restrict__ rend,
                                                 const unsigned short* __restrict__ featb,
                                                 float* __restrict__ out,
                                                 int col_off, int N) {
    int row  = blockIdx.x * 4 + (threadIdx.x >> 6);
    if (row >= N) return;
    int lane = threadIdx.x & 63;
    int j = lane & 15;
    int h = lane >> 4;
    int s = rstart[row], e = rend[row];

    float4 acc0 = {0.f, 0.f, 0.f, 0.f};
    float4 acc1 = {0.f, 0.f, 0.f, 0.f};
    int i = s;
    for (; i + 16 <= e; i += 16) {
        uint2 eA = ep[i + h];
        uint2 eB = ep[i + 4 + h];
        uint2 eC = ep[i + 8 + h];
        uint2 eD = ep[i + 12 + h];
        uint4 gA = *(const uint4*)&featb[(size_t)eA.x * D + j * 8];
        uint4 gB = *(const uint4*)&featb[(size_t)eB.x * D + j * 8];
        uint4 gC = *(const uint4*)&featb[(size_t)eC.x * D + j * 8];
        uint4 gD = *(const uint4*)&featb[(size_t)eD.x * D + j * 8];
        ACCQ(eA.y, gA);
        ACCQ(eB.y, gB);
        ACCQ(eC.y, gC);
        ACCQ(eD.y, gD);
    }
    for (; i + 8 <= e; i += 8) {
        uint2 eA = ep[i + h];
        uint2 eB = ep[i + 4 + h];
        uint4 gA = *(const uint4*)&featb[(size_t)eA.x * D + j * 8];
        uint4 gB = *(const uint4*)&featb[(size_t)eB.x * D + j * 8];
        ACCQ(eA.y, gA);
        ACCQ(eB.y, gB);
    }
    for (; i < e; i += 4) {
        int idx = i + h;
        uint2 ev = make_uint2(0u, 0u);
        if (idx < e) ev = ep[idx];
        uint4 g = *(const uint4*)&featb[(size_t)ev.x * D + j * 8];
        ACCQ(ev.y, g);
    }

#pragma unroll
    for (int m = 16; m <= 32; m <<= 1) {
        acc0.x += __shfl_xor(acc0.x, m);
        acc0.y += __shfl_xor(acc0.y, m);
        acc0.z += __shfl_xor(acc0.z, m);
        acc0.w += __shfl_xor(acc0.w, m);
        acc1.x += __shfl_xor(acc1.x, m);
        acc1.y += __shfl_xor(acc1.y, m);
        acc1.z += __shfl_xor(acc1.z, m);
        acc1.w += __shfl_xor(acc1.w, m);
    }

    acc0.x = (acc0.x > 0.f) ? acc0.x : SLOPE * acc0.x;
    acc0.y = (acc0.y > 0.f) ? acc0.y : SLOPE * acc0.y;
    acc0.z = (acc0.z > 0.f) ? acc0.z : SLOPE * acc0.z;
    acc0.w = (acc0.w > 0.f) ? acc0.w : SLOPE * acc0.w;
    acc1.x = (acc1.x > 0.f) ? acc1.x : SLOPE * acc1.x;
    acc1.y = (acc1.y > 0.f) ? acc1.y : SLOPE * acc1.y;
    acc1.z = (acc1.z > 0.f) ? acc1.z : SLOPE * acc1.z;
    acc1.w = (acc1.w > 0.f) ? acc1.w : SLOPE * acc1.w;

    float ss = acc0.x * acc0.x + acc0.y * acc0.y + acc0.z * acc0.z + acc0.w * acc0.w
             + acc1.x * acc1.x + acc1.y * acc1.y + acc1.z * acc1.z + acc1.w * acc1.w;
#pragma unroll
    for (int m = 8; m >= 1; m >>= 1) ss += __shfl_xor(ss, m);
    float sc = 1.0f / fmaxf(sqrtf(ss), 1e-12f);

    if (h == 0) {
        float* dst = &out[(size_t)row * OUTD + col_off + j * 8];
        float4 o0 = {acc0.x * sc, acc0.y * sc, acc0.z * sc, acc0.w * sc};
        float4 o1 = {acc1.x * sc, acc1.y * sc, acc1.z * sc, acc1.w * sc};
        *(float4*)&dst[0] = o0;
        *(float4*)&dst[4] = o1;
    }
}

extern "C" void kernel_launch(void* const* d_in, const int* in_sizes, int n_in,
                              void* d_out, int out_size, void* d_ws, size_t ws_size,
                              hipStream_t stream) {
    const int*   rows = (const int*)d_in[0];
    const int*   cols = (const int*)d_in[1];
    const float* vals = (const float*)d_in[2];
    const float* ue   = (const float*)d_in[3];
    const float* ie   = (const float*)d_in[4];
    const float* uw0  = (const float*)d_in[5];
    const float* vw0  = (const float*)d_in[6];
    const float* uw1  = (const float*)d_in[7];
    const float* vw1  = (const float*)d_in[8];
    float* out = (float*)d_out;

    int nnz = in_sizes[0];
    int U   = in_sizes[3] / D;
    int I   = in_sizes[4] / D;
    int N   = U + I;
    int NB  = (N + BROWS - 1) >> BSH;

    int avg = nnz / NB;
    int cap = avg + avg / 8 + 64;       // ~8 sigma slack for binomial bucket sizes
    if (cap > FCAP) cap = FCAP;

    // workspace layout
    char* p = (char*)d_ws;
    unsigned short* featb = (unsigned short*)p;  p += (size_t)N * D * 2;            // 38.4 MB
    uint2* edges          = (uint2*)p;           p += (size_t)NB * cap * 8;         // ~43.8 MB
    int* row_start        = (int*)p;             p += (size_t)N * 4;
    int* rend             = (int*)p;             p += (size_t)N * 4;
    float* nsave          = (float*)p;           p += (size_t)N * 4;
    p = (char*)(((size_t)p + 63) & ~(size_t)63);
    int* bcursor          = (int*)p;             p += (size_t)NB * 64;              // padded
    unsigned short* wtbuf = (unsigned short*)p;  p += (size_t)4 * 16384 * 2;        // 128 KB

    int row_blocks = (N + 3) / 4;
    int gu = (U + GR - 1) / GR;
    int gi = (I + GR - 1) / GR;
    int sc_blocks = (nnz + SPAN - 1) / SPAN;

    // ---- prep: weight transpose (once) + cursor init ----
    wt_prep<<<4, 256, 0, stream>>>(uw0, vw0, uw1, vw1, wtbuf);
    init_cursors<<<(NB + 255) / 256, 256, 0, stream>>>(bcursor, NB, cap);

    // ---- CSR scatter (bucket-chunked, unsorted within bucket) ----
    chunk_scatter<<<sc_blocks, SCT, 0, stream>>>(rows, cols, vals, bcursor, edges,
                                                 nnz, NB, cap);

    // ---- layer 0: gemm (bf16 out, + raw f32 rows -> out[0:128)) ----
    gemm_mfma<<<gu, 256, 0, stream>>>(ue, D, wtbuf, featb, nullptr, out, U);
    gemm_mfma<<<gi, 256, 0, stream>>>(ie, D, wtbuf + 16384, featb + (size_t)U * D,
                                      nullptr, out + (size_t)U * OUTD, I);

    // ---- fused: per-bucket sort (writes sorted edges + row_start/rend) + layer-0 spmm
    spmm_sort_fused<<<NB, FTH, 0, stream>>>(bcursor, edges, row_start, rend, featb,
                                            out, nsave, D, N, cap);

    // ---- layer 1: gemm reads normalized out cols * nsave (recovers unnormalized) ----
    gemm_mfma<<<gu, 256, 0, stream>>>(out + D, OUTD, wtbuf + 2 * 16384, featb,
                                      nsave, nullptr, U);
    gemm_mfma<<<gi, 256, 0, stream>>>(out + (size_t)U * OUTD + D, OUTD, wtbuf + 3 * 16384,
                                      featb + (size_t)U * D, nsave + U, nullptr, I);
    spmm_csr4<<<row_blocks, 256, 0, stream>>>(edges, row_start, rend, featb, out,
                                              2 * D, N);
}

// Round 14
// 583.275 us; speedup vs baseline: 1.1117x; 1.1117x over previous
//
#include <hip/hip_runtime.h>

#define D 128
#define OUTD 384
#define SLOPE 0.2f
#define BSH 7                  // bucket = row >> 7  (128 rows/bucket)
#define BROWS 128
#define MAXNB 2048
#define FCAP 4736              // bucket LDS stage capacity (avg 4096 + slack)
#define SPAN 8192              // edges per scatter segment
#define SCT 512
#define FTH 512
#define NSMAX 1024

typedef __attribute__((ext_vector_type(8))) short bf16x8;
typedef __attribute__((ext_vector_type(4))) float f32x4;

__device__ __forceinline__ unsigned f2bf(float f) {   // round-to-nearest-even bf16
    unsigned u = __float_as_uint(f);
    return (u + 0x7FFFu + ((u >> 16) & 1u)) >> 16;
}

__device__ __forceinline__ void nt_store_f4(float4 v, float* p) {
    f32x4 t = {v.x, v.y, v.z, v.w};
    __builtin_nontemporal_store(t, (f32x4*)p);
}

// ---------------- one-time weight prep: Wt[n][k] = bf16(W[k][n]) ----------------
__global__ __launch_bounds__(256) void wt_prep(const float* __restrict__ W0,
                                               const float* __restrict__ W1,
                                               const float* __restrict__ W2,
                                               const float* __restrict__ W3,
                                               unsigned short* __restrict__ wt) {
    const float* Ws[4] = {W0, W1, W2, W3};
    const float* W = Ws[blockIdx.x];
    unsigned short* o = wt + (size_t)blockIdx.x * 16384;
    for (int i = threadIdx.x; i < 16384; i += 256) {
        int k = i >> 7, n = i & 127;
        o[(size_t)n * 128 + k] = (unsigned short)f2bf(W[(size_t)k * 128 + n]);
    }
}

// ---------------- MFMA GEMM: featb[r] = bf16( (rowscale[r]*in[r*pitch]) @ W ) -------------
#define GR 64
#define APAD 136
__global__ __launch_bounds__(256) void gemm_mfma(const float* __restrict__ in, int pitch,
                                                 const unsigned short* __restrict__ Wt,
                                                 unsigned short* __restrict__ featb,
                                                 const float* __restrict__ rowscale,
                                                 float* __restrict__ rawout,
                                                 int nrows) {
    __shared__ unsigned short sA[GR * APAD];     // 17.4 KB
    __shared__ unsigned short sW[128 * APAD];    // 34.8 KB
    int tid = threadIdx.x;
    int row0 = blockIdx.x * GR;
    int nr = min(GR, nrows - row0);

    for (int i = tid; i < GR * 32; i += 256) {
        int r = i >> 5, c4 = (i & 31) * 4;
        unsigned lo = 0, hi = 0;
        if (r < nr) {
            float4 t = *(const float4*)&in[(size_t)(row0 + r) * pitch + c4];
            if (rawout)
                nt_store_f4(t, &rawout[(size_t)(row0 + r) * OUTD + c4]);
            if (rowscale) {
                float s = rowscale[row0 + r];
                t.x *= s; t.y *= s; t.z *= s; t.w *= s;
            }
            lo = f2bf(t.x) | (f2bf(t.y) << 16);
            hi = f2bf(t.z) | (f2bf(t.w) << 16);
        }
        uint2 pk = {lo, hi};
        *(uint2*)&sA[r * APAD + c4] = pk;
    }
    for (int i = tid; i < 128 * 16; i += 256) {
        int n = i >> 4, k8 = (i & 15) * 8;
        *(uint4*)&sW[n * APAD + k8] = *(const uint4*)&Wt[(size_t)n * 128 + k8];
    }
    __syncthreads();

    int l  = tid & 63;
    int w  = tid >> 6;
    int lr = l & 15;
    int lk = (l >> 4) * 8;

    f32x4 acc[8];
#pragma unroll
    for (int t = 0; t < 8; ++t) acc[t] = (f32x4){0.f, 0.f, 0.f, 0.f};

#pragma unroll
    for (int k0 = 0; k0 < 128; k0 += 32) {
        bf16x8 af = *(const bf16x8*)&sA[(16 * w + lr) * APAD + k0 + lk];
#pragma unroll
        for (int t = 0; t < 8; ++t) {
            bf16x8 bf = *(const bf16x8*)&sW[(t * 16 + lr) * APAD + k0 + lk];
            acc[t] = __builtin_amdgcn_mfma_f32_16x16x32_bf16(af, bf, acc[t], 0, 0, 0);
        }
    }

    int rbase = 16 * w + (l >> 4) * 4;
#pragma unroll
    for (int t = 0; t < 8; ++t) {
#pragma unroll
        for (int q = 0; q < 4; ++q) {
            int r = rbase + q;
            if (r < nr)
                featb[(size_t)(row0 + r) * D + t * 16 + lr] = (unsigned short)f2bf(acc[t][q]);
        }
    }
}

// ================= segment-local scatter =================
// Block s owns edges [s*SPAN, s*SPAN+SPAN): groups them by bucket within its PRIVATE
// etmp window (base s*SPAN) — perfect write combining, no global atomics — and emits
// its bucket-offset row offmat[s][0..NB] (off[NB] = segment length).
__global__ __launch_bounds__(SCT) void seg_scatter(const int* __restrict__ rows,
                                                   const int* __restrict__ cols,
                                                   const float* __restrict__ vals,
                                                   uint2* __restrict__ etmp,
                                                   int* __restrict__ offmat,
                                                   int nnz, int NB) {
    __shared__ int hist[MAXNB];
    __shared__ int wsum[8];
    int tid = threadIdx.x;
    int sgm = blockIdx.x;
    int lo  = sgm * SPAN;
    int hi  = min(lo + SPAN, nnz);
    if (lo >= nnz) return;

    for (int i = tid; i < NB; i += SCT) hist[i] = 0;
    __syncthreads();

    // pass 1: reg-stage rows (single read) + bucket count
    int4 r4[4];
#pragma unroll
    for (int q = 0; q < 4; ++q) {
        int e = lo + (q * SCT + tid) * 4;
        if (e + 3 < hi) {
            r4[q] = *(const int4*)&rows[e];
            atomicAdd(&hist[r4[q].x >> BSH], 1);
            atomicAdd(&hist[r4[q].y >> BSH], 1);
            atomicAdd(&hist[r4[q].z >> BSH], 1);
            atomicAdd(&hist[r4[q].w >> BSH], 1);
        } else {
            int t0 = (e + 0 < hi) ? rows[e + 0] : -1;
            int t1 = (e + 1 < hi) ? rows[e + 1] : -1;
            int t2 = (e + 2 < hi) ? rows[e + 2] : -1;
            int t3 = (e + 3 < hi) ? rows[e + 3] : -1;
            if (t0 >= 0) atomicAdd(&hist[t0 >> BSH], 1);
            if (t1 >= 0) atomicAdd(&hist[t1 >> BSH], 1);
            if (t2 >= 0) atomicAdd(&hist[t2 >> BSH], 1);
            if (t3 >= 0) atomicAdd(&hist[t3 >> BSH], 1);
            r4[q] = make_int4(t0, t1, t2, t3);
        }
    }
    __syncthreads();

    // exclusive scan of hist[0..NB); convert hist to local cursors; emit offmat row
    int per = (NB + SCT - 1) / SCT;             // <= 4 for NB <= 2048
    int base = tid * per;
    int lv[4];
    int lsum = 0;
#pragma unroll
    for (int k = 0; k < 4; ++k) {
        int idx = base + k;
        int v = (k < per && idx < NB) ? hist[idx] : 0;
        lv[k] = v; lsum += v;
    }
    int lane = tid & 63, wid = tid >> 6;
    int incl = lsum;
#pragma unroll
    for (int off = 1; off < 64; off <<= 1) {
        int t = __shfl_up(incl, off);
        if (lane >= off) incl += t;
    }
    if (lane == 63) wsum[wid] = incl;
    __syncthreads();
    int woff = 0;
    for (int w = 0; w < wid; ++w) woff += wsum[w];
    int run = woff + incl - lsum;
    __syncthreads();                             // everyone done reading hist counts
    int rowbase = sgm * (NB + 1);
#pragma unroll
    for (int k = 0; k < 4; ++k) {
        int idx = base + k;
        if (k < per && idx < NB) {
            int c = lv[k];
            hist[idx] = run;
            offmat[rowbase + idx] = run;
            run += c;
        }
    }
    if (NB - 1 >= base && NB - 1 < base + per)
        offmat[rowbase + NB] = run;              // segment length
    __syncthreads();

    // pass 3: emit into private window (local positions)
#define SEMIT(r, c, v)                                                             \
    {                                                                              \
        int pos_ = atomicAdd(&hist[(r) >> BSH], 1);                                \
        etmp[lo + pos_] = make_uint2(((unsigned)((r) & (BROWS - 1)) << 18) |       \
                                     (unsigned)(c), __float_as_uint(v));           \
    }
#pragma unroll
    for (int q = 0; q < 4; ++q) {
        int e = lo + (q * SCT + tid) * 4;
        if (e + 3 < hi) {
            int4   c4 = *(const int4*)&cols[e];
            float4 v4 = *(const float4*)&vals[e];
            SEMIT(r4[q].x, c4.x, v4.x);
            SEMIT(r4[q].y, c4.y, v4.y);
            SEMIT(r4[q].z, c4.z, v4.z);
            SEMIT(r4[q].w, c4.w, v4.w);
        } else {
            int rr0 = r4[q].x, rr1 = r4[q].y, rr2 = r4[q].z, rr3 = r4[q].w;
            if (rr0 >= 0) { SEMIT(rr0, cols[e + 0], vals[e + 0]); }
            if (rr1 >= 0) { SEMIT(rr1, cols[e + 1], vals[e + 1]); }
            if (rr2 >= 0) { SEMIT(rr2, cols[e + 2], vals[e + 2]); }
            if (rr3 >= 0) { SEMIT(rr3, cols[e + 3], vals[e + 3]); }
        }
    }
}

// ================= per-bucket gather + row sort =================
// Block b gathers its NS chunks (via offmat columns b,b+1), stages in LDS, sorts by
// row, writes to cap-strided esort + row_start/rend.
__global__ __launch_bounds__(FTH) void seg_finalize(const uint2* __restrict__ etmp,
                                                    const int* __restrict__ offmat,
                                                    uint2* __restrict__ esort,
                                                    int* __restrict__ row_start,
                                                    int* __restrict__ rend,
                                                    int N, int NB, int NS, int cap) {
    __shared__ uint2 ed[FCAP];                   // 37.9 KB
    __shared__ int srcoff[NSMAX], slen[NSMAX], dstoff[NSMAX];
    __shared__ int rcnt[BROWS], rbase[BROWS];
    __shared__ int wsum[8];
    __shared__ int tot;
    int b   = blockIdx.x;
    int tid = threadIdx.x;
    int lane = tid & 63, wid = tid >> 6;
    if (tid < BROWS) rcnt[tid] = 0;

    // read my chunks' (offset,len) from offmat column b / b+1
    int per = (NS + FTH - 1) / FTH;             // <= 2 for NS <= 1024
    int base = tid * per;
    int lo0[2], ll[2];
    int lsum = 0;
#pragma unroll
    for (int k = 0; k < 2; ++k) {
        int s = base + k;
        int o0 = 0, l = 0;
        if (k < per && s < NS) {
            int rb = s * (NB + 1) + b;
            o0 = offmat[rb];
            l  = offmat[rb + 1] - o0;
        }
        lo0[k] = o0; ll[k] = l; lsum += l;
    }
    int incl = lsum;
#pragma unroll
    for (int off = 1; off < 64; off <<= 1) {
        int t = __shfl_up(incl, off);
        if (lane >= off) incl += t;
    }
    if (lane == 63) wsum[wid] = incl;
    __syncthreads();
    int woff = 0;
    for (int w = 0; w < wid; ++w) woff += wsum[w];
    int run = woff + incl - lsum;
#pragma unroll
    for (int k = 0; k < 2; ++k) {
        int s = base + k;
        if (k < per && s < NS) {
            srcoff[s] = lo0[k];
            slen[s]   = ll[k];
            dstoff[s] = run;
            run += ll[k];
        }
    }
    if (NS - 1 >= base && NS - 1 < base + per) tot = min(run, cap);
    __syncthreads();

    // gather chunks into LDS + per-row count
#pragma unroll
    for (int k = 0; k < 2; ++k) {
        int s = base + k;
        if (k < per && s < NS) {
            int src = s * SPAN + srcoff[s];
            int dst = dstoff[s];
            int l   = slen[s];
            if (dst + l > cap) l = max(0, cap - dst);   // ~9-sigma guard
            for (int i2 = 0; i2 < l; ++i2) {
                uint2 t = etmp[src + i2];
                ed[dst + i2] = t;
                atomicAdd(&rcnt[t.x >> 18], 1);
            }
        }
    }
    __syncthreads();

    // exclusive scan of 128 row counts (2 waves)
    int c = (tid < BROWS) ? rcnt[tid] : 0;
    int incl2 = c;
#pragma unroll
    for (int off = 1; off < 64; off <<= 1) {
        int t = __shfl_up(incl2, off);
        if (lane >= off) incl2 += t;
    }
    if (tid < BROWS && lane == 63) wsum[wid] = incl2;
    __syncthreads();
    if (tid < BROWS) {
        int woff2 = (wid == 1) ? wsum[0] : 0;
        int excl = woff2 + incl2 - c;
        rbase[tid] = b * cap + excl;
        int row = b * BROWS + tid;
        if (row < N) { row_start[row] = b * cap + excl; rend[row] = b * cap + excl + c; }
    }
    __syncthreads();

    // permute to row-sorted order
    int tl = tot;
    for (int i2 = tid; i2 < tl; i2 += FTH) {
        uint2 t = ed[i2];
        int pos = atomicAdd(&rbase[t.x >> 18], 1);
        esort[pos] = make_uint2(t.x & 0x3FFFFu, t.y);
    }
}

// ================= CSR SpMM v4: wave per row, 4 edges per gather instruction ==========
#define ACCQ(vbits, g)                                             \
    {                                                              \
        float v = __uint_as_float(vbits);                          \
        acc0.x += v * __uint_as_float((g).x << 16);                \
        acc0.y += v * __uint_as_float((g).x & 0xFFFF0000u);        \
        acc0.z += v * __uint_as_float((g).y << 16);                \
        acc0.w += v * __uint_as_float((g).y & 0xFFFF0000u);        \
        acc1.x += v * __uint_as_float((g).z << 16);                \
        acc1.y += v * __uint_as_float((g).z & 0xFFFF0000u);        \
        acc1.z += v * __uint_as_float((g).w << 16);                \
        acc1.w += v * __uint_as_float((g).w & 0xFFFF0000u);        \
    }

__global__ __launch_bounds__(256) void spmm_csr4(const uint2* __restrict__ ep,
                                                 const int* __restrict__ rstart,
                                                 const int* __restrict__ rend,
                                                 const unsigned short* __restrict__ featb,
                                                 float* __restrict__ out,
                                                 float* __restrict__ nsave,
                                                 int col_off, int N) {
    int row  = blockIdx.x * 4 + (threadIdx.x >> 6);
    if (row >= N) return;
    int lane = threadIdx.x & 63;
    int j = lane & 15;      // dim group
    int h = lane >> 4;      // edge slot
    int s = rstart[row], e = rend[row];

    float4 acc0 = {0.f, 0.f, 0.f, 0.f};
    float4 acc1 = {0.f, 0.f, 0.f, 0.f};
    int i = s;
    for (; i + 16 <= e; i += 16) {
        uint2 eA = ep[i + h];
        uint2 eB = ep[i + 4 + h];
        uint2 eC = ep[i + 8 + h];
        uint2 eD = ep[i + 12 + h];
        uint4 gA = *(const uint4*)&featb[(size_t)eA.x * D + j * 8];
        uint4 gB = *(const uint4*)&featb[(size_t)eB.x * D + j * 8];
        uint4 gC = *(const uint4*)&featb[(size_t)eC.x * D + j * 8];
        uint4 gD = *(const uint4*)&featb[(size_t)eD.x * D + j * 8];
        ACCQ(eA.y, gA);
        ACCQ(eB.y, gB);
        ACCQ(eC.y, gC);
        ACCQ(eD.y, gD);
    }
    for (; i + 8 <= e; i += 8) {
        uint2 eA = ep[i + h];
        uint2 eB = ep[i + 4 + h];
        uint4 gA = *(const uint4*)&featb[(size_t)eA.x * D + j * 8];
        uint4 gB = *(const uint4*)&featb[(size_t)eB.x * D + j * 8];
        ACCQ(eA.y, gA);
        ACCQ(eB.y, gB);
    }
    for (; i < e; i += 4) {
        int idx = i + h;
        uint2 ev = make_uint2(0u, 0u);          // col 0 / val 0: harmless dummy
        if (idx < e) ev = ep[idx];
        uint4 g = *(const uint4*)&featb[(size_t)ev.x * D + j * 8];
        ACCQ(ev.y, g);
    }

#pragma unroll
    for (int m = 16; m <= 32; m <<= 1) {
        acc0.x += __shfl_xor(acc0.x, m);
        acc0.y += __shfl_xor(acc0.y, m);
        acc0.z += __shfl_xor(acc0.z, m);
        acc0.w += __shfl_xor(acc0.w, m);
        acc1.x += __shfl_xor(acc1.x, m);
        acc1.y += __shfl_xor(acc1.y, m);
        acc1.z += __shfl_xor(acc1.z, m);
        acc1.w += __shfl_xor(acc1.w, m);
    }

    acc0.x = (acc0.x > 0.f) ? acc0.x : SLOPE * acc0.x;
    acc0.y = (acc0.y > 0.f) ? acc0.y : SLOPE * acc0.y;
    acc0.z = (acc0.z > 0.f) ? acc0.z : SLOPE * acc0.z;
    acc0.w = (acc0.w > 0.f) ? acc0.w : SLOPE * acc0.w;
    acc1.x = (acc1.x > 0.f) ? acc1.x : SLOPE * acc1.x;
    acc1.y = (acc1.y > 0.f) ? acc1.y : SLOPE * acc1.y;
    acc1.z = (acc1.z > 0.f) ? acc1.z : SLOPE * acc1.z;
    acc1.w = (acc1.w > 0.f) ? acc1.w : SLOPE * acc1.w;

    float ss = acc0.x * acc0.x + acc0.y * acc0.y + acc0.z * acc0.z + acc0.w * acc0.w
             + acc1.x * acc1.x + acc1.y * acc1.y + acc1.z * acc1.z + acc1.w * acc1.w;
#pragma unroll
    for (int m = 8; m >= 1; m >>= 1) ss += __shfl_xor(ss, m);
    float nm = fmaxf(sqrtf(ss), 1e-12f);
    float sc = 1.0f / nm;

    if (nsave && lane == 0) nsave[row] = nm;
    if (h == 0) {
        float* dst = &out[(size_t)row * OUTD + col_off + j * 8];
        float4 o0 = {acc0.x * sc, acc0.y * sc, acc0.z * sc, acc0.w * sc};
        float4 o1 = {acc1.x * sc, acc1.y * sc, acc1.z * sc, acc1.w * sc};
        *(float4*)&dst[0] = o0;
        *(float4*)&dst[4] = o1;
    }
}

extern "C" void kernel_launch(void* const* d_in, const int* in_sizes, int n_in,
                              void* d_out, int out_size, void* d_ws, size_t ws_size,
                              hipStream_t stream) {
    const int*   rows = (const int*)d_in[0];
    const int*   cols = (const int*)d_in[1];
    const float* vals = (const float*)d_in[2];
    const float* ue   = (const float*)d_in[3];
    const float* ie   = (const float*)d_in[4];
    const float* uw0  = (const float*)d_in[5];
    const float* vw0  = (const float*)d_in[6];
    const float* uw1  = (const float*)d_in[7];
    const float* vw1  = (const float*)d_in[8];
    float* out = (float*)d_out;

    int nnz = in_sizes[0];
    int U   = in_sizes[3] / D;
    int I   = in_sizes[4] / D;
    int N   = U + I;
    int NB  = (N + BROWS - 1) >> BSH;
    int NS  = (nnz + SPAN - 1) / SPAN;

    int avg = nnz / NB;
    int cap = avg + avg / 8 + 64;       // ~9 sigma slack for binomial bucket sizes
    if (cap > FCAP) cap = FCAP;

    // workspace layout (etmp overlays featb: etmp dead before gemms write featb)
    char* p = (char*)d_ws;
    size_t unionSz = (size_t)N * D * 2;
    if ((size_t)nnz * 8 > unionSz) unionSz = (size_t)nnz * 8;
    unsigned short* featb = (unsigned short*)p;
    uint2*          etmp  = (uint2*)p;           p += unionSz;                      // 38.4 MB
    uint2* esort          = (uint2*)p;           p += (size_t)NB * cap * 8;         // ~43.8 MB
    int* row_start        = (int*)p;             p += (size_t)N * 4;
    int* rend             = (int*)p;             p += (size_t)N * 4;
    float* nsave          = (float*)p;           p += (size_t)N * 4;
    p = (char*)(((size_t)p + 63) & ~(size_t)63);
    int* offmat           = (int*)p;             p += (size_t)NS * (NB + 1) * 4;    // ~2.8 MB
    p = (char*)(((size_t)p + 63) & ~(size_t)63);
    unsigned short* wtbuf = (unsigned short*)p;  p += (size_t)4 * 16384 * 2;        // 128 KB

    int row_blocks = (N + 3) / 4;
    int gu = (U + GR - 1) / GR;
    int gi = (I + GR - 1) / GR;

    // ---- prep ----
    wt_prep<<<4, 256, 0, stream>>>(uw0, vw0, uw1, vw1, wtbuf);

    // ---- CSR build: segment-local scatter -> per-bucket gather+sort ----
    seg_scatter<<<NS, SCT, 0, stream>>>(rows, cols, vals, etmp, offmat, nnz, NB);
    seg_finalize<<<NB, FTH, 0, stream>>>(etmp, offmat, esort, row_start, rend,
                                         N, NB, NS, cap);

    // ---- layer 0: gemm (bf16 out, + raw f32 rows -> out[0:128)) -> spmm (norm, save n)
    gemm_mfma<<<gu, 256, 0, stream>>>(ue, D, wtbuf, featb, nullptr, out, U);
    gemm_mfma<<<gi, 256, 0, stream>>>(ie, D, wtbuf + 16384, featb + (size_t)U * D,
                                      nullptr, out + (size_t)U * OUTD, I);
    spmm_csr4<<<row_blocks, 256, 0, stream>>>(esort, row_start, rend, featb, out,
                                              nsave, D, N);

    // ---- layer 1: gemm reads normalized out cols * nsave (recovers unnormalized) ----
    gemm_mfma<<<gu, 256, 0, stream>>>(out + D, OUTD, wtbuf + 2 * 16384, featb,
                                      nsave, nullptr, U);
    gemm_mfma<<<gi, 256, 0, stream>>>(out + (size_t)U * OUTD + D, OUTD, wtbuf + 3 * 16384,
                                      featb + (size_t)U * D, nsave + U, nullptr, I);
    spmm_csr4<<<row_blocks, 256, 0, stream>>>(esort, row_start, rend, featb, out,
                                              nullptr, 2 * D, N);
}